// Round 11
// baseline (333.145 us; speedup 1.0000x reference)
//
#include <hip/hip_runtime.h>
#include <hip/hip_fp16.h>

// 3-layer gather-GEMM GNN (N=262144, K=8, 16->128->128->16), f16 MFMA.
// Round 11: deepen gather pipelines (the round-10 limiter was in-flight
// gather bytes, ~2.3 KB/wave):
//  L1: 2-deep gather ping-pong (ga[2][4]) — gather for nb+2 issued at iter nb,
//      consumed at staging end of iter nb+1 (~2 compute phases of cover).
//      Index ring refills idx(nb+4). LDS/swizzle unchanged (0 conflicts).
//  L2: rolling A prefetch depth 3 -> 4 (a[4][4]), refill idx[nb+4].
// L0 unchanged. Scaled messages prescaled by 2^-8; epilogue x256 + bias.
//
// Workspace: ws holds ONLY h1+h2 (128 MiB exactly). invd/h16/shuffled-W live
// in d_out (scratch until layer 2 overwrites it); layer 2's invd+Wf2 are
// d2d-copied into the dead h1 region first.

typedef _Float16 f16x8 __attribute__((ext_vector_type(8)));
typedef float f32x4 __attribute__((ext_vector_type(4)));

#define NNODES 262144

__global__ __launch_bounds__(256) void conv_h_kernel(const float* __restrict__ h,
                                                     __half* __restrict__ h16, int n) {
    int i = blockIdx.x * 256 + threadIdx.x;
    if (i < n) h16[i] = __float2half(h[i]);
}

__global__ __launch_bounds__(256) void prep_edges_kernel(const float* __restrict__ pos,
                                                         const int* __restrict__ nbr,
                                                         __half* __restrict__ invd, int n_edges) {
    int e = blockIdx.x * 256 + threadIdx.x;
    if (e >= n_edges) return;
    int i = e >> 3;
    int n = nbr[e];
    float dx = pos[i * 3 + 0] - pos[n * 3 + 0];
    float dy = pos[i * 3 + 1] - pos[n * 3 + 1];
    float dz = pos[i * 3 + 2] - pos[n * 3 + 2];
    float d = sqrtf(dx * dx + dy * dy + dz * dz);
    if (d == 0.0f) d = 0.5f;                       // reference: where(dist==0, 0.5, dist)
    invd[e] = __float2half((1.0f / d) * 0.00390625f);  // prescale 1/256
}

// Pre-shuffle W [KT][FO] (row-major f32) into MFMA B-fragment order:
// Wf[((s*NT + t)*64 + lane)*8 + j] = W[s*32 + (lane>>4)*8 + j][t*16 + (lane&15)]
__global__ __launch_bounds__(256) void shuffle_w_kernel(const float* __restrict__ W,
                                                        __half* __restrict__ Wf,
                                                        int KT, int FO) {
    int e = blockIdx.x * 256 + threadIdx.x;
    if (e >= KT * FO) return;
    int j = e & 7;
    int lane = (e >> 3) & 63;
    int rest = e >> 9;
    int NT = FO >> 4;
    int t = rest % NT;
    int s = rest / NT;
    int k = s * 32 + (lane >> 4) * 8 + j;
    int n = t * 16 + (lane & 15);
    Wf[e] = __float2half(W[k * FO + n]);
}

// ---------------- L0: F_IN=16, F_OUT=128, 128 rows/block ----------------
__global__ __launch_bounds__(256) void layer0_kernel(
    const __half* __restrict__ hprev, const __half* __restrict__ invd,
    const int* __restrict__ nbr, const __half* __restrict__ Wf,
    const float* __restrict__ bias, __half* __restrict__ outp) {
    __shared__ __align__(16) __half Bs[16384];  // 32 KB weights, staged once

    const int tid = threadIdx.x;
    const int wave = tid >> 6;
    const int lane = tid & 63;
    const int quad = lane >> 4;
    const int lmod = lane & 15;
    const int mbase = blockIdx.x * 128 + wave * 16 + lmod;

    int idx[2][8];
    f16x8 invr[2];
#pragma unroll
    for (int mt = 0; mt < 2; ++mt) {
        const int m = mbase + mt * 64;
        const int4* nrow = (const int4*)(nbr + (size_t)m * 8);
        const int4 iA = nrow[0];
        const int4 iB = nrow[1];
        idx[mt][0] = iA.x; idx[mt][1] = iA.y; idx[mt][2] = iA.z; idx[mt][3] = iA.w;
        idx[mt][4] = iB.x; idx[mt][5] = iB.y; idx[mt][6] = iB.z; idx[mt][7] = iB.w;
        invr[mt] = *(const f16x8*)(invd + (size_t)m * 8);
    }

    f32x4 acc[2][8];
#pragma unroll
    for (int mt = 0; mt < 2; ++mt)
#pragma unroll
        for (int t = 0; t < 8; ++t) acc[mt][t] = f32x4{0.f, 0.f, 0.f, 0.f};

    {
        const uint4* src = (const uint4*)Wf;
        uint4* dst = (uint4*)Bs;
#pragma unroll
        for (int i = 0; i < 8; ++i) dst[i * 256 + tid] = src[i * 256 + tid];
    }
    __syncthreads();

#pragma unroll
    for (int s = 0; s < 4; ++s) {
        const int nb = 2 * s + (quad >> 1);
        f16x8 as[2];
#pragma unroll
        for (int mt = 0; mt < 2; ++mt) {
            f16x8 av = *(const f16x8*)(hprev + (size_t)idx[mt][nb] * 16 + (quad & 1) * 8);
            as[mt] = av * invr[mt][nb];
        }
#pragma unroll
        for (int t = 0; t < 8; ++t) {
            f16x8 b = *(const f16x8*)(Bs + ((size_t)(s * 8 + t) * 64 + lane) * 8);
#pragma unroll
            for (int mt = 0; mt < 2; ++mt)
                acc[mt][t] = __builtin_amdgcn_mfma_f32_16x16x32_f16(as[mt], b, acc[mt][t], 0, 0, 0);
        }
    }

#pragma unroll
    for (int mt = 0; mt < 2; ++mt) {
        const int rbase = blockIdx.x * 128 + mt * 64 + wave * 16 + quad * 4;
#pragma unroll
        for (int t = 0; t < 8; ++t) {
            const int col = t * 16 + lmod;
            const float bv = bias[col];
#pragma unroll
            for (int rr = 0; rr < 4; ++rr) {
                float v = acc[mt][t][rr] * 256.0f + bv;
                outp[(size_t)(rbase + rr) * 128 + col] = __float2half(v);
            }
        }
    }
}

// ---------------- L1: F_IN=128, F_OUT=128, 64 rows/block, t-specialized ----
// LDS: seg-major + XOR swizzle, 16B granules: off16(seg,row) =
//   seg*64 + (row & ~15) + ((row ^ seg) & 15)   -> spans [0, 1024) granules.
__device__ __forceinline__ int off16(int seg, int row) {
    return seg * 64 + (row & ~15) + ((row ^ seg) & 15);
}

__global__ __launch_bounds__(256, 3) void layer1_kernel(
    const __half* __restrict__ hprev, const __half* __restrict__ invd,
    const int* __restrict__ nbr, const __half* __restrict__ Wf,
    const float* __restrict__ bias, __half* __restrict__ outp) {
    __shared__ __align__(16) __half As[2][8192];  // 2 x 1024 granules x 16B = 32 KB

    const int tid = threadIdx.x;
    const int wave = tid >> 6;
    const int lane = tid & 63;
    const int quad = lane >> 4;
    const int lmod = lane & 15;
    const int rowblk = blockIdx.x * 64;
    const int seg = lmod;  // staging: this thread's 16B segment

    // Staging rows for this wave: 4 insts x 4 rows (quad picks row-in-inst).
    int srow[4], grow_[4], soff[4];
#pragma unroll
    for (int i = 0; i < 4; ++i) {
        srow[i] = wave * 16 + i * 4 + quad;
        grow_[i] = rowblk + srow[i];
        soff[i] = off16(seg, srow[i]) * 8;  // halves
    }

    f16x8 invS[4];
#pragma unroll
    for (int i = 0; i < 4; ++i) invS[i] = *(const f16x8*)(invd + (size_t)grow_[i] * 8);

    // Direct idx for nb0/nb1; 2-slot ring for nb>=2:
    // invariant at start of iter nb: idxR[nb&1] = idx(nb+2).
    int idxA[4], idxB[4], idxR[2][4];
#pragma unroll
    for (int i = 0; i < 4; ++i) {
        idxA[i] = nbr[(size_t)grow_[i] * 8 + 0];
        idxB[i] = nbr[(size_t)grow_[i] * 8 + 1];
        idxR[0][i] = nbr[(size_t)grow_[i] * 8 + 2];
        idxR[1][i] = nbr[(size_t)grow_[i] * 8 + 3];
    }

    // This wave's two output col-tiles: t = wave*2 + tl.
    const __half* WfB = Wf + ((size_t)(wave * 2) * 64 + lane) * 8;

    f16x8 Bc[4][2], Bn[4][2];
#pragma unroll
    for (int ks = 0; ks < 4; ++ks)
#pragma unroll
        for (int tl = 0; tl < 2; ++tl)
            Bc[ks][tl] = *(const f16x8*)(WfB + (size_t)(ks * 8 + tl) * 512);

    // Fragment-read offsets (halves): seg=ks*4+quad, row=m*16+lmod.
    int roff[4][4];
#pragma unroll
    for (int m = 0; m < 4; ++m)
#pragma unroll
        for (int ks = 0; ks < 4; ++ks)
            roff[m][ks] = off16(ks * 4 + quad, m * 16 + lmod) * 8;

    // 2-deep gather ping-pong: issue nb0 and nb1 before the first barrier.
    f16x8 ga[2][4];
#pragma unroll
    for (int i = 0; i < 4; ++i)
        ga[0][i] = *(const f16x8*)(hprev + (size_t)idxA[i] * 128 + seg * 8);
#pragma unroll
    for (int i = 0; i < 4; ++i)
        ga[1][i] = *(const f16x8*)(hprev + (size_t)idxB[i] * 128 + seg * 8);

    // Stage nb=0.
#pragma unroll
    for (int i = 0; i < 4; ++i) {
        f16x8 v = ga[0][i] * invS[i][0];
        *(f16x8*)(&As[0][soff[i]]) = v;
    }
    __syncthreads();

    f32x4 acc[4][2];
#pragma unroll
    for (int m = 0; m < 4; ++m) { acc[m][0] = f32x4{0.f,0.f,0.f,0.f}; acc[m][1] = f32x4{0.f,0.f,0.f,0.f}; }

#pragma unroll
    for (int nb = 0; nb < 8; ++nb) {
        const int cur = nb & 1;
        // Issue gathers for nb+2 into the slot freed by nb's staging (iter nb-1).
        if (nb < 6) {
#pragma unroll
            for (int i = 0; i < 4; ++i)
                ga[cur][i] = *(const f16x8*)(hprev + (size_t)idxR[cur][i] * 128 + seg * 8);
        }
        // Refill the index ring: idx(nb+4) into the slot just consumed.
        if (nb < 4) {
#pragma unroll
            for (int i = 0; i < 4; ++i)
                idxR[cur][i] = nbr[(size_t)grow_[i] * 8 + nb + 4];
        }
        // Issue B-fragment loads for nb+1 (L2-resident stream).
        if (nb < 7) {
#pragma unroll
            for (int ks = 0; ks < 4; ++ks)
#pragma unroll
                for (int tl = 0; tl < 2; ++tl)
                    Bn[ks][tl] = *(const f16x8*)(WfB + (size_t)(((nb + 1) * 4 + ks) * 8 + tl) * 512);
        }
        // Compute nb: 16 ds_read_b128, 32 MFMA (each A frag feeds 2 MFMAs).
#pragma unroll
        for (int m = 0; m < 4; ++m) {
#pragma unroll
            for (int ks = 0; ks < 4; ++ks) {
                f16x8 a = *(const f16x8*)(&As[cur][roff[m][ks]]);
                acc[m][0] = __builtin_amdgcn_mfma_f32_16x16x32_f16(a, Bc[ks][0], acc[m][0], 0, 0, 0);
                acc[m][1] = __builtin_amdgcn_mfma_f32_16x16x32_f16(a, Bc[ks][1], acc[m][1], 0, 0, 0);
            }
        }
        // Stage nb+1 (gathered at iter nb-1) into the other buffer; rotate B.
        if (nb < 7) {
#pragma unroll
            for (int i = 0; i < 4; ++i) {
                f16x8 v = ga[(nb + 1) & 1][i] * invS[i][nb + 1];
                *(f16x8*)(&As[cur ^ 1][soff[i]]) = v;
            }
#pragma unroll
            for (int ks = 0; ks < 4; ++ks) { Bc[ks][0] = Bn[ks][0]; Bc[ks][1] = Bn[ks][1]; }
            __syncthreads();
        }
    }

    // Epilogue: rows 0..63, cols wave*32..+32. LeakyReLU.
#pragma unroll
    for (int m = 0; m < 4; ++m) {
#pragma unroll
        for (int tl = 0; tl < 2; ++tl) {
            const int col = wave * 32 + tl * 16 + lmod;
            const float bv = bias[col];
#pragma unroll
            for (int rr = 0; rr < 4; ++rr) {
                const int grow = rowblk + m * 16 + quad * 4 + rr;
                float v = acc[m][tl][rr] * 256.0f + bv;
                v = (v >= 0.f) ? v : 0.01f * v;
                outp[(size_t)grow * 128 + col] = __float2half(v);
            }
        }
    }
}

// ---------------- L2: F_IN=128, F_OUT=16, 64 rows/block, rolling gather ----
__global__ __launch_bounds__(256) void layer2_kernel(
    const __half* __restrict__ hprev, const __half* __restrict__ invd,
    const int* __restrict__ nbr, const __half* __restrict__ Wf,
    const float* __restrict__ bias, float* __restrict__ outp) {
    __shared__ __align__(16) __half Bs[16384];  // 32 KB weights, staged once

    const int tid = threadIdx.x;
    const int wave = tid >> 6;
    const int lane = tid & 63;
    const int quad = lane >> 4;
    const int lmod = lane & 15;
    const int m = blockIdx.x * 64 + wave * 16 + lmod;

    const int4* nrow = (const int4*)(nbr + (size_t)m * 8);
    const int4 iA = nrow[0];
    const int4 iB = nrow[1];
    const int idx[8] = {iA.x, iA.y, iA.z, iA.w, iB.x, iB.y, iB.z, iB.w};
    const f16x8 invr = *(const f16x8*)(invd + (size_t)m * 8);

    {
        const uint4* src = (const uint4*)Wf;
        uint4* dst = (uint4*)Bs;
#pragma unroll
        for (int i = 0; i < 8; ++i) dst[i * 256 + tid] = src[i * 256 + tid];
    }
    __syncthreads();

    // Rolling 4-deep neighbor prefetch; barrier-free loop.
    f16x8 a[4][4];
#pragma unroll
    for (int d = 0; d < 4; ++d)
#pragma unroll
        for (int ks = 0; ks < 4; ++ks)
            a[d][ks] = *(const f16x8*)(hprev + (size_t)idx[d] * 128 + ks * 32 + quad * 8);

    f32x4 acc = f32x4{0.f, 0.f, 0.f, 0.f};
#pragma unroll
    for (int nb = 0; nb < 8; ++nb) {
        const int slot = nb & 3;
#pragma unroll
        for (int ks = 0; ks < 4; ++ks) {
            f16x8 as = a[slot][ks] * invr[nb];
            f16x8 b = *(const f16x8*)(Bs + ((size_t)(nb * 4 + ks) * 64 + lane) * 8);
            acc = __builtin_amdgcn_mfma_f32_16x16x32_f16(as, b, acc, 0, 0, 0);
        }
        if (nb < 4) {
#pragma unroll
            for (int ks = 0; ks < 4; ++ks)
                a[slot][ks] = *(const f16x8*)(hprev + (size_t)idx[nb + 4] * 128 + ks * 32 + quad * 8);
        }
    }

    const int rbase = blockIdx.x * 64 + wave * 16 + quad * 4;
    const float bv = bias[lmod];
#pragma unroll
    for (int rr = 0; rr < 4; ++rr)
        outp[(size_t)(rbase + rr) * 16 + lmod] = acc[rr] * 256.0f + bv;
}

extern "C" void kernel_launch(void* const* d_in, const int* in_sizes, int n_in,
                              void* d_out, int out_size, void* d_ws, size_t ws_size,
                              hipStream_t stream) {
    const float* h   = (const float*)d_in[0];
    const float* pos = (const float*)d_in[1];
    const int*   nbr = (const int*)d_in[2];
    const float* W0  = (const float*)d_in[3];
    const float* b0  = (const float*)d_in[4];
    const float* W1  = (const float*)d_in[5];
    const float* b1  = (const float*)d_in[6];
    const float* W2  = (const float*)d_in[7];
    const float* b2  = (const float*)d_in[8];

    const int N = NNODES;

    // ws: ONLY the two 64 MiB fp16 intermediates (128 MiB total).
    char* w = (char*)d_ws;
    __half* h1 = (__half*)w;                               // 67,108,864 B
    __half* h2 = (__half*)(w + (size_t)67108864);          // 67,108,864 B
    // layer-2 copies of invd/Wf2, placed in the dead h1 region:
    __half* invd2 = (__half*)w;                            // 4,194,304 B
    __half* W2f2  = (__half*)(w + (size_t)4194304);        // 32,768 B

    // d_out doubles as scratch until layer 2 overwrites all of it (16 MiB).
    char* ob = (char*)d_out;
    __half* invd = (__half*)(ob + 0);                      // 4,194,304 B
    __half* h16  = (__half*)(ob + 4194304);                // 8,388,608 B
    __half* W0f  = (__half*)(ob + 12582912);               // 32,768 B
    __half* W1f  = (__half*)(ob + 12615680);               // 262,144 B
    __half* W2f  = (__half*)(ob + 12877824);               // 32,768 B  (end 12,910,592 <= 16,777,216)

    conv_h_kernel<<<(N * 16 + 255) / 256, 256, 0, stream>>>(h, h16, N * 16);
    prep_edges_kernel<<<(N * 8 + 255) / 256, 256, 0, stream>>>(pos, nbr, invd, N * 8);
    shuffle_w_kernel<<<(128 * 128 + 255) / 256, 256, 0, stream>>>(W0, W0f, 128, 128);
    shuffle_w_kernel<<<(1024 * 128 + 255) / 256, 256, 0, stream>>>(W1, W1f, 1024, 128);
    shuffle_w_kernel<<<(1024 * 16 + 255) / 256, 256, 0, stream>>>(W2, W2f, 1024, 16);

    layer0_kernel<<<N / 128, 256, 0, stream>>>(h16, invd, nbr, W0f, b0, h1);
    layer1_kernel<<<N / 64, 256, 0, stream>>>(h1, invd, nbr, W1f, b1, h2);

    // Move what layer 2 needs out of d_out (h1 is dead now).
    (void)hipMemcpyAsync(invd2, invd, 4194304, hipMemcpyDeviceToDevice, stream);
    (void)hipMemcpyAsync(W2f2, W2f, 32768, hipMemcpyDeviceToDevice, stream);

    layer2_kernel<<<N / 64, 256, 0, stream>>>(h2, invd2, nbr, W2f2, b2, (float*)d_out);
}

// Round 12
// 315.065 us; speedup vs baseline: 1.0574x; 1.0574x over previous
//
#include <hip/hip_runtime.h>
#include <hip/hip_fp16.h>

// 3-layer gather-GEMM GNN (N=262144, K=8, 16->128->128->16), f16 MFMA.
// Round 12: eliminate the L2-layer's 512 MB logical gather via factorization:
//   out[i] = 256 * sum_k invd[i,k] * P[nbr[i,k]][k*16..+16] + b2,
//   P[s][k*16+c] = sum_f h2[s][f] * W2[k*128+f][c]
// P ([N,128] fp16) is computed INSIDE layer1's epilogue (h2 tile is already in
// registers; C->A relayout through the same XOR-swizzled LDS buffer, then a
// 256-MFMA tile GEMM with W2-stacked fragments) — h2 never hits memory.
// The old gather-heavy layer2 becomes a light 32 B/edge reduce kernel.
// L1 main loop = round-11 (2-deep gather ping-pong, 0 bank conflicts).
// Scaled messages prescaled by 2^-8; P holds true h2@W2s; reduce applies
// invd(pre) then x256.
//
// Workspace: ws = h1 (64 MiB) + P (64 MiB) = 128 MiB exactly. invd/h16/Wf live
// in d_out scratch; invd is d2d-copied into dead h1 before the reduce (which
// writes d_out).

typedef _Float16 f16x8 __attribute__((ext_vector_type(8)));
typedef float f32x4 __attribute__((ext_vector_type(4)));

#define NNODES 262144

__global__ __launch_bounds__(256) void conv_h_kernel(const float* __restrict__ h,
                                                     __half* __restrict__ h16, int n) {
    int i = blockIdx.x * 256 + threadIdx.x;
    if (i < n) h16[i] = __float2half(h[i]);
}

__global__ __launch_bounds__(256) void prep_edges_kernel(const float* __restrict__ pos,
                                                         const int* __restrict__ nbr,
                                                         __half* __restrict__ invd, int n_edges) {
    int e = blockIdx.x * 256 + threadIdx.x;
    if (e >= n_edges) return;
    int i = e >> 3;
    int n = nbr[e];
    float dx = pos[i * 3 + 0] - pos[n * 3 + 0];
    float dy = pos[i * 3 + 1] - pos[n * 3 + 1];
    float dz = pos[i * 3 + 2] - pos[n * 3 + 2];
    float d = sqrtf(dx * dx + dy * dy + dz * dz);
    if (d == 0.0f) d = 0.5f;                       // reference: where(dist==0, 0.5, dist)
    invd[e] = __float2half((1.0f / d) * 0.00390625f);  // prescale 1/256
}

// Pre-shuffle W [KT][FO] (row-major f32) into MFMA B-fragment order:
// Wf[((s*NT + t)*64 + lane)*8 + j] = W[s*32 + (lane>>4)*8 + j][t*16 + (lane&15)]
__global__ __launch_bounds__(256) void shuffle_w_kernel(const float* __restrict__ W,
                                                        __half* __restrict__ Wf,
                                                        int KT, int FO) {
    int e = blockIdx.x * 256 + threadIdx.x;
    if (e >= KT * FO) return;
    int j = e & 7;
    int lane = (e >> 3) & 63;
    int rest = e >> 9;
    int NT = FO >> 4;
    int t = rest % NT;
    int s = rest / NT;
    int k = s * 32 + (lane >> 4) * 8 + j;
    int n = t * 16 + (lane & 15);
    Wf[e] = __float2half(W[k * FO + n]);
}

// Fragment-order for the STACKED W2: W2s[k][t*16+c] = W2[t*128+k][c]
// (W2 row-major [1024][16]; KT=128, FO=128 -> NT=8).
__global__ __launch_bounds__(256) void shuffle_w2s_kernel(const float* __restrict__ W2,
                                                          __half* __restrict__ Wf) {
    int e = blockIdx.x * 256 + threadIdx.x;
    if (e >= 128 * 128) return;
    int j = e & 7;
    int lane = (e >> 3) & 63;
    int rest = e >> 9;
    int t = rest % 8;
    int s = rest / 8;
    int k = s * 32 + (lane >> 4) * 8 + j;
    Wf[e] = __float2half(W2[(size_t)(t * 128 + k) * 16 + (lane & 15)]);
}

// ---------------- L0: F_IN=16, F_OUT=128, 128 rows/block ----------------
__global__ __launch_bounds__(256) void layer0_kernel(
    const __half* __restrict__ hprev, const __half* __restrict__ invd,
    const int* __restrict__ nbr, const __half* __restrict__ Wf,
    const float* __restrict__ bias, __half* __restrict__ outp) {
    __shared__ __align__(16) __half Bs[16384];  // 32 KB weights, staged once

    const int tid = threadIdx.x;
    const int wave = tid >> 6;
    const int lane = tid & 63;
    const int quad = lane >> 4;
    const int lmod = lane & 15;
    const int mbase = blockIdx.x * 128 + wave * 16 + lmod;

    int idx[2][8];
    f16x8 invr[2];
#pragma unroll
    for (int mt = 0; mt < 2; ++mt) {
        const int m = mbase + mt * 64;
        const int4* nrow = (const int4*)(nbr + (size_t)m * 8);
        const int4 iA = nrow[0];
        const int4 iB = nrow[1];
        idx[mt][0] = iA.x; idx[mt][1] = iA.y; idx[mt][2] = iA.z; idx[mt][3] = iA.w;
        idx[mt][4] = iB.x; idx[mt][5] = iB.y; idx[mt][6] = iB.z; idx[mt][7] = iB.w;
        invr[mt] = *(const f16x8*)(invd + (size_t)m * 8);
    }

    f32x4 acc[2][8];
#pragma unroll
    for (int mt = 0; mt < 2; ++mt)
#pragma unroll
        for (int t = 0; t < 8; ++t) acc[mt][t] = f32x4{0.f, 0.f, 0.f, 0.f};

    {
        const uint4* src = (const uint4*)Wf;
        uint4* dst = (uint4*)Bs;
#pragma unroll
        for (int i = 0; i < 8; ++i) dst[i * 256 + tid] = src[i * 256 + tid];
    }
    __syncthreads();

#pragma unroll
    for (int s = 0; s < 4; ++s) {
        const int nb = 2 * s + (quad >> 1);
        f16x8 as[2];
#pragma unroll
        for (int mt = 0; mt < 2; ++mt) {
            f16x8 av = *(const f16x8*)(hprev + (size_t)idx[mt][nb] * 16 + (quad & 1) * 8);
            as[mt] = av * invr[mt][nb];
        }
#pragma unroll
        for (int t = 0; t < 8; ++t) {
            f16x8 b = *(const f16x8*)(Bs + ((size_t)(s * 8 + t) * 64 + lane) * 8);
#pragma unroll
            for (int mt = 0; mt < 2; ++mt)
                acc[mt][t] = __builtin_amdgcn_mfma_f32_16x16x32_f16(as[mt], b, acc[mt][t], 0, 0, 0);
        }
    }

#pragma unroll
    for (int mt = 0; mt < 2; ++mt) {
        const int rbase = blockIdx.x * 128 + mt * 64 + wave * 16 + quad * 4;
#pragma unroll
        for (int t = 0; t < 8; ++t) {
            const int col = t * 16 + lmod;
            const float bv = bias[col];
#pragma unroll
            for (int rr = 0; rr < 4; ++rr) {
                float v = acc[mt][t][rr] * 256.0f + bv;
                outp[(size_t)(rbase + rr) * 128 + col] = __float2half(v);
            }
        }
    }
}

// ------- L1+P: F_IN=128, F_OUT=128, 64 rows/block, fused P projection -------
// LDS: seg-major + XOR swizzle, 16B granules: off16(seg,row) =
//   seg*64 + (row & ~15) + ((row ^ seg) & 15)   -> spans [0, 1024) granules.
__device__ __forceinline__ int off16(int seg, int row) {
    return seg * 64 + (row & ~15) + ((row ^ seg) & 15);
}

__global__ __launch_bounds__(256, 3) void layer1p_kernel(
    const __half* __restrict__ hprev, const __half* __restrict__ invd,
    const int* __restrict__ nbr, const __half* __restrict__ Wf,
    const __half* __restrict__ Wf2s, const float* __restrict__ bias,
    __half* __restrict__ Pout) {
    __shared__ __align__(16) __half As[2][8192];  // 2 x 1024 granules x 16B = 32 KB

    const int tid = threadIdx.x;
    const int wave = tid >> 6;
    const int lane = tid & 63;
    const int quad = lane >> 4;
    const int lmod = lane & 15;
    const int rowblk = blockIdx.x * 64;
    const int seg = lmod;  // staging: this thread's 16B segment

    int srow[4], grow_[4], soff[4];
#pragma unroll
    for (int i = 0; i < 4; ++i) {
        srow[i] = wave * 16 + i * 4 + quad;
        grow_[i] = rowblk + srow[i];
        soff[i] = off16(seg, srow[i]) * 8;  // halves
    }

    f16x8 invS[4];
#pragma unroll
    for (int i = 0; i < 4; ++i) invS[i] = *(const f16x8*)(invd + (size_t)grow_[i] * 8);

    // Direct idx for nb0/nb1; 2-slot ring for nb>=2 (idxR[nb&1] = idx(nb+2)).
    int idxA[4], idxB[4], idxR[2][4];
#pragma unroll
    for (int i = 0; i < 4; ++i) {
        idxA[i] = nbr[(size_t)grow_[i] * 8 + 0];
        idxB[i] = nbr[(size_t)grow_[i] * 8 + 1];
        idxR[0][i] = nbr[(size_t)grow_[i] * 8 + 2];
        idxR[1][i] = nbr[(size_t)grow_[i] * 8 + 3];
    }

    // This wave's two output col-tiles: t = wave*2 + tl.
    const __half* WfB = Wf + ((size_t)(wave * 2) * 64 + lane) * 8;

    f16x8 Bc[4][2], Bn[4][2];
#pragma unroll
    for (int ks = 0; ks < 4; ++ks)
#pragma unroll
        for (int tl = 0; tl < 2; ++tl)
            Bc[ks][tl] = *(const f16x8*)(WfB + (size_t)(ks * 8 + tl) * 512);

    // Fragment-read offsets (halves): seg=ks*4+quad, row=m*16+lmod.
    int roff[4][4];
#pragma unroll
    for (int m = 0; m < 4; ++m)
#pragma unroll
        for (int ks = 0; ks < 4; ++ks)
            roff[m][ks] = off16(ks * 4 + quad, m * 16 + lmod) * 8;

    // 2-deep gather ping-pong.
    f16x8 ga[2][4];
#pragma unroll
    for (int i = 0; i < 4; ++i)
        ga[0][i] = *(const f16x8*)(hprev + (size_t)idxA[i] * 128 + seg * 8);
#pragma unroll
    for (int i = 0; i < 4; ++i)
        ga[1][i] = *(const f16x8*)(hprev + (size_t)idxB[i] * 128 + seg * 8);

#pragma unroll
    for (int i = 0; i < 4; ++i) {
        f16x8 v = ga[0][i] * invS[i][0];
        *(f16x8*)(&As[0][soff[i]]) = v;
    }
    __syncthreads();

    f32x4 acc[4][2];
#pragma unroll
    for (int m = 0; m < 4; ++m) { acc[m][0] = f32x4{0.f,0.f,0.f,0.f}; acc[m][1] = f32x4{0.f,0.f,0.f,0.f}; }

#pragma unroll
    for (int nb = 0; nb < 8; ++nb) {
        const int cur = nb & 1;
        if (nb < 6) {
#pragma unroll
            for (int i = 0; i < 4; ++i)
                ga[cur][i] = *(const f16x8*)(hprev + (size_t)idxR[cur][i] * 128 + seg * 8);
        }
        if (nb < 4) {
#pragma unroll
            for (int i = 0; i < 4; ++i)
                idxR[cur][i] = nbr[(size_t)grow_[i] * 8 + nb + 4];
        }
        if (nb < 7) {
#pragma unroll
            for (int ks = 0; ks < 4; ++ks)
#pragma unroll
                for (int tl = 0; tl < 2; ++tl)
                    Bn[ks][tl] = *(const f16x8*)(WfB + (size_t)(((nb + 1) * 4 + ks) * 8 + tl) * 512);
        }
#pragma unroll
        for (int m = 0; m < 4; ++m) {
#pragma unroll
            for (int ks = 0; ks < 4; ++ks) {
                f16x8 a = *(const f16x8*)(&As[cur][roff[m][ks]]);
                acc[m][0] = __builtin_amdgcn_mfma_f32_16x16x32_f16(a, Bc[ks][0], acc[m][0], 0, 0, 0);
                acc[m][1] = __builtin_amdgcn_mfma_f32_16x16x32_f16(a, Bc[ks][1], acc[m][1], 0, 0, 0);
            }
        }
        if (nb < 7) {
#pragma unroll
            for (int i = 0; i < 4; ++i) {
                f16x8 v = ga[(nb + 1) & 1][i] * invS[i][nb + 1];
                *(f16x8*)(&As[cur ^ 1][soff[i]]) = v;
            }
#pragma unroll
            for (int ks = 0; ks < 4; ++ks) { Bc[ks][0] = Bn[ks][0]; Bc[ks][1] = Bn[ks][1]; }
            __syncthreads();
        }
    }

    // ---- Fused epilogue: h2 = leaky(acc*256 + b1) -> LDS (swizzled) ----
    // As[0] is free: its last reader was nb=6's compute, before the last
    // barrier. h2 tile = 64 rows x 128 cols, element (row,col) at granule
    // off16(col>>3, row), half (col&7).
    __half* As0 = &As[0][0];
#pragma unroll
    for (int m = 0; m < 4; ++m) {
#pragma unroll
        for (int tl = 0; tl < 2; ++tl) {
            const int col = wave * 32 + tl * 16 + lmod;
            const float bv = bias[col];
            const int sg = col >> 3;
            const int jj = col & 7;
#pragma unroll
            for (int rr = 0; rr < 4; ++rr) {
                const int row = m * 16 + quad * 4 + rr;
                float v = acc[m][tl][rr] * 256.0f + bv;
                v = (v >= 0.f) ? v : 0.01f * v;
                As0[off16(sg, row) * 8 + jj] = __float2half(v);
            }
        }
    }
    __syncthreads();

    // ---- P = h2 @ W2s (K=128, 4 k-steps); wave owns col-tiles wave*2+tl ----
    const __half* WfB2 = Wf2s + ((size_t)(wave * 2) * 64 + lane) * 8;
    f16x8 B2[4][2];
#pragma unroll
    for (int ks = 0; ks < 4; ++ks)
#pragma unroll
        for (int tl = 0; tl < 2; ++tl)
            B2[ks][tl] = *(const f16x8*)(WfB2 + (size_t)(ks * 8 + tl) * 512);

    f32x4 acc2[4][2];
#pragma unroll
    for (int m = 0; m < 4; ++m) { acc2[m][0] = f32x4{0.f,0.f,0.f,0.f}; acc2[m][1] = f32x4{0.f,0.f,0.f,0.f}; }
#pragma unroll
    for (int m = 0; m < 4; ++m) {
#pragma unroll
        for (int ks = 0; ks < 4; ++ks) {
            f16x8 a2 = *(const f16x8*)(&As0[roff[m][ks]]);
            acc2[m][0] = __builtin_amdgcn_mfma_f32_16x16x32_f16(a2, B2[ks][0], acc2[m][0], 0, 0, 0);
            acc2[m][1] = __builtin_amdgcn_mfma_f32_16x16x32_f16(a2, B2[ks][1], acc2[m][1], 0, 0, 0);
        }
    }

    // ---- write P (fp16, true scale) ----
#pragma unroll
    for (int m = 0; m < 4; ++m) {
#pragma unroll
        for (int tl = 0; tl < 2; ++tl) {
            const int col = wave * 32 + tl * 16 + lmod;
#pragma unroll
            for (int rr = 0; rr < 4; ++rr) {
                const int grow = rowblk + m * 16 + quad * 4 + rr;
                Pout[(size_t)grow * 128 + col] = __float2half(acc2[m][tl][rr]);
            }
        }
    }
}

// ---------------- Reduce: out[i] = 256*sum_k invd[i,k]*P[nbr[i,k]][k*16..]+b2
__global__ __launch_bounds__(256) void reduce_kernel(
    const __half* __restrict__ P, const __half* __restrict__ invd,
    const int* __restrict__ nbr, const float* __restrict__ b2,
    float* __restrict__ outp) {
    const int d = blockIdx.x * 256 + threadIdx.x;

    const int4* nrow = (const int4*)(nbr + (size_t)d * 8);
    const int4 iA = nrow[0];
    const int4 iB = nrow[1];
    const int idx[8] = {iA.x, iA.y, iA.z, iA.w, iB.x, iB.y, iB.z, iB.w};
    const f16x8 iv = *(const f16x8*)(invd + (size_t)d * 8);

    // Issue all 16 gather loads up front.
    f16x8 lo[8], hi[8];
#pragma unroll
    for (int k = 0; k < 8; ++k) {
        const __half* p = P + (size_t)idx[k] * 128 + k * 16;
        lo[k] = *(const f16x8*)p;
        hi[k] = *(const f16x8*)(p + 8);
    }

    float acc[16];
#pragma unroll
    for (int c = 0; c < 16; ++c) acc[c] = 0.f;
#pragma unroll
    for (int k = 0; k < 8; ++k) {
        const float w = (float)iv[k];
#pragma unroll
        for (int c = 0; c < 8; ++c) {
            acc[c] += w * (float)lo[k][c];
            acc[c + 8] += w * (float)hi[k][c];
        }
    }

    float4 o[4];
#pragma unroll
    for (int q = 0; q < 4; ++q) {
        o[q].x = acc[q * 4 + 0] * 256.0f + b2[q * 4 + 0];
        o[q].y = acc[q * 4 + 1] * 256.0f + b2[q * 4 + 1];
        o[q].z = acc[q * 4 + 2] * 256.0f + b2[q * 4 + 2];
        o[q].w = acc[q * 4 + 3] * 256.0f + b2[q * 4 + 3];
    }
    float4* dst = (float4*)(outp + (size_t)d * 16);
#pragma unroll
    for (int q = 0; q < 4; ++q) dst[q] = o[q];
}

extern "C" void kernel_launch(void* const* d_in, const int* in_sizes, int n_in,
                              void* d_out, int out_size, void* d_ws, size_t ws_size,
                              hipStream_t stream) {
    const float* h   = (const float*)d_in[0];
    const float* pos = (const float*)d_in[1];
    const int*   nbr = (const int*)d_in[2];
    const float* W0  = (const float*)d_in[3];
    const float* b0  = (const float*)d_in[4];
    const float* W1  = (const float*)d_in[5];
    const float* b1  = (const float*)d_in[6];
    const float* W2  = (const float*)d_in[7];
    const float* b2  = (const float*)d_in[8];

    const int N = NNODES;

    // ws: h1 (64 MiB) + P (64 MiB) = 128 MiB exactly.
    char* w = (char*)d_ws;
    __half* h1 = (__half*)w;                               // 67,108,864 B
    __half* P  = (__half*)(w + (size_t)67108864);          // 67,108,864 B
    __half* invd2 = (__half*)w;                            // 4 MiB, into dead h1

    // d_out doubles as scratch until reduce overwrites all of it (16 MiB).
    char* ob = (char*)d_out;
    __half* invd = (__half*)(ob + 0);                      // 4,194,304 B
    __half* h16  = (__half*)(ob + 4194304);                // 8,388,608 B
    __half* W0f  = (__half*)(ob + 12582912);               // 32,768 B
    __half* W1f  = (__half*)(ob + 12615680);               // 262,144 B
    __half* Wf2s = (__half*)(ob + 12877824);               // 32,768 B (end 12,910,592)

    conv_h_kernel<<<(N * 16 + 255) / 256, 256, 0, stream>>>(h, h16, N * 16);
    prep_edges_kernel<<<(N * 8 + 255) / 256, 256, 0, stream>>>(pos, nbr, invd, N * 8);
    shuffle_w_kernel<<<(128 * 128 + 255) / 256, 256, 0, stream>>>(W0, W0f, 128, 128);
    shuffle_w_kernel<<<(1024 * 128 + 255) / 256, 256, 0, stream>>>(W1, W1f, 1024, 128);
    shuffle_w2s_kernel<<<(128 * 128 + 255) / 256, 256, 0, stream>>>(W2, Wf2s);

    layer0_kernel<<<N / 128, 256, 0, stream>>>(h16, invd, nbr, W0f, b0, h1);
    layer1p_kernel<<<N / 64, 256, 0, stream>>>(h1, invd, nbr, W1f, Wf2s, b1, P);

    // h1 is dead now; move invd out of d_out before reduce writes d_out.
    (void)hipMemcpyAsync(invd2, invd, 4194304, hipMemcpyDeviceToDevice, stream);

    reduce_kernel<<<N / 256, 256, 0, stream>>>(P, invd2, nbr, b2, (float*)d_out);
}